// Round 22
// baseline (427.553 us; speedup 1.0000x reference)
//
#include <hip/hip_runtime.h>
#include <hip/hip_fp16.h>
#include <cstddef>
#include <cstdint>

#define N_NODES 100000
typedef unsigned int uint;
typedef unsigned short u16;
typedef __attribute__((ext_vector_type(8))) short bf16x8;
typedef __attribute__((ext_vector_type(4))) float f32x4;

// ---- bf16 helpers (bit-exact unpack, RNE pack) ------------------------------
__device__ __forceinline__ float bflo(uint u) { return __uint_as_float(u << 16); }
__device__ __forceinline__ float bfhi(uint u) { return __uint_as_float(u & 0xffff0000u); }
__device__ __forceinline__ uint bf_rne(float f) {
    uint u = __float_as_uint(f);
    return (u + 0x7fffu + ((u >> 16) & 1u)) >> 16;
}
__device__ __forceinline__ uint bfpack(float a, float b) {
    return bf_rne(a) | (bf_rne(b) << 16);
}
union U4H { uint4 u; __half2 h[4]; };
union UH  { uint u; __half2 h; };

// ---------------------------------------------------------------------------
// Degree via per-CU LDS histogram, u8-packed (4 ids per u32 word).
#define HBINS 25000   // 100000/4 words, 100KB LDS
#define NSL 128       // slices (must match fill_det)
__global__ __launch_bounds__(256) void hist_kernel(
    const int* __restrict__ src, const int* __restrict__ dst, int E,
    uint* __restrict__ partialU, uint* __restrict__ partialR) {
    __shared__ uint h[HBINS];
    int b = blockIdx.x;
    const int* ids = (b < NSL) ? src : dst;
    uint* out = ((b < NSL) ? partialU : partialR);
    int slice = (b < NSL) ? b : b - NSL;
    for (int i = threadIdx.x; i < HBINS; i += 256) h[i] = 0;
    __syncthreads();
    int per = (E + NSL - 1) / NSL;
    int lo = slice * per, hi = min(E, lo + per);
    for (int i = lo + threadIdx.x; i < hi; i += 256) {
        int id = ids[i];
        atomicAdd(&h[id >> 2], 1u << ((id & 3) * 8));
    }
    __syncthreads();
    out += (size_t)slice * HBINS;
    for (int i = threadIdx.x; i < HBINS; i += 256) out[i] = h[i];
}

// Reduce per-slice histograms -> degrees, AND replace partials in place with
// the packed-u8 EXCLUSIVE PREFIX over slices (per node). Safe: degree << 255.
__global__ __launch_bounds__(256) void histreduce(
    uint* __restrict__ partialU, uint* __restrict__ partialR,
    int* __restrict__ degU, int* __restrict__ degR) {
    int idx = blockIdx.x * blockDim.x + threadIdx.x;
    if (idx >= 2 * HBINS) return;
    uint* p = (idx < HBINS) ? partialU : partialR;
    int* deg = (idx < HBINS) ? degU : degR;
    int w = (idx < HBINS) ? idx : idx - HBINS;
    uint r0 = 0, r1 = 0, r2 = 0, r3 = 0;
    for (int b = 0; b < NSL; ++b) {
        size_t k = (size_t)b * HBINS + w;
        uint v = p[k];
        p[k] = r0 | (r1 << 8) | (r2 << 16) | (r3 << 24);   // exclusive prefix
        r0 += v & 255u; r1 += (v >> 8) & 255u; r2 += (v >> 16) & 255u; r3 += v >> 24;
    }
    *(int4*)(deg + 4 * w) = make_int4((int)r0, (int)r1, (int)r2, (int)r3);
}

// ---------------------------------------------------------------------------
// Multi-block exclusive scan of degrees.
#define CHUNK 4096
#define SNB ((N_NODES + CHUNK - 1) / CHUNK)

__global__ __launch_bounds__(256) void scanA(
    const int* __restrict__ degU, const int* __restrict__ degR,
    int* __restrict__ bsum, int n) {
    int b = blockIdx.x;
    int side = b / SNB, blk = b % SNB;
    const int* deg = side ? degR : degU;
    int base = blk * CHUNK;
    int tid = threadIdx.x;
    int s = 0;
    #pragma unroll
    for (int k = 0; k < 16; ++k) {
        int i = base + k * 256 + tid;
        if (i < n) s += deg[i];
    }
    #pragma unroll
    for (int o = 32; o; o >>= 1) s += __shfl_xor(s, o);
    __shared__ int ws[4];
    if ((tid & 63) == 0) ws[tid >> 6] = s;
    __syncthreads();
    if (tid == 0) bsum[b] = ws[0] + ws[1] + ws[2] + ws[3];
}

__global__ void scanB(const int* __restrict__ bsum, int* __restrict__ bpre) {
    if (threadIdx.x == 0) {
        int run = 0;
        for (int i = 0; i < 2 * SNB; ++i) {
            if (i == SNB) run = 0;      // side boundary reset
            bpre[i] = run;
            run += bsum[i];
        }
    }
}

__global__ __launch_bounds__(256) void scanC(
    const int* __restrict__ degU, int* __restrict__ offU, float* __restrict__ normU,
    const int* __restrict__ degR, int* __restrict__ offR, float* __restrict__ normR,
    const int* __restrict__ bpre, int n) {
    int b = blockIdx.x;
    int side = b / SNB, blk = b % SNB;
    const int* deg = side ? degR : degU;
    int* off = side ? offR : offU;
    float* nrm = side ? normR : normU;
    int base = blk * CHUNK;
    int tid = threadIdx.x;
    int p0 = base + tid * 16;
    int e[16];
    #pragma unroll
    for (int k = 0; k < 16; ++k) {
        int i = p0 + k;
        e[k] = (i < n) ? deg[i] : 0;
    }
    int loc = 0;
    #pragma unroll
    for (int k = 0; k < 16; ++k) loc += e[k];
    int lane = tid & 63, wv = tid >> 6;
    int x = loc;
    #pragma unroll
    for (int o = 1; o < 64; o <<= 1) {
        int y = __shfl_up(x, o);
        if (lane >= o) x += y;
    }
    __shared__ int wsum[4];
    if (lane == 63) wsum[wv] = x;
    __syncthreads();
    int wvOff = 0;
    for (int i = 0; i < wv; ++i) wvOff += wsum[i];
    int run = bpre[b] + wvOff + (x - loc);
    if (blk == 0 && tid == 0) off[0] = 0;
    #pragma unroll
    for (int k = 0; k < 16; ++k) {
        int i = p0 + k;
        if (i < n) {
            int v = e[k];
            nrm[i] = (v > 0) ? (1.0f / sqrtf((float)v)) : 0.f;
            run += v;
            off[i + 1] = run;
        }
    }
}

// ---------------------------------------------------------------------------
// Deterministic CSR fill: ZERO global atomics.
__global__ __launch_bounds__(256) void fill_det(
    const int* __restrict__ src, const int* __restrict__ dst, int E,
    const uint* __restrict__ prefS, const uint* __restrict__ prefD,
    const int* __restrict__ offS, const int* __restrict__ offD,
    int* __restrict__ colS, int* __restrict__ colD) {
    __shared__ uint cur[3125];            // 12500-node range, u8-packed
    int b = blockIdx.x;
    int side = b >> 10;                   // 0: src-CSR, 1: dst-CSR
    int r = b & 1023;
    int x = r & 7;                        // XCD node-range
    int slice = r >> 3;                   // 0..127
    const int* ids = side ? dst : src;
    const int* oth = side ? src : dst;
    const uint* pref = (side ? prefD : prefS) + (size_t)slice * HBINS;
    const int* off = side ? offD : offS;
    int* col = side ? colD : colS;
    for (int i = threadIdx.x; i < 3125; i += 256) cur[i] = 0;
    __syncthreads();
    int per = (E + NSL - 1) / NSL;
    int lo = slice * per, hi = min(E, lo + per);
    int rlo = x * 12500;
    for (int i = lo + threadIdx.x; i < hi; i += 256) {
        int id = ids[i];
        unsigned local = (unsigned)(id - rlo);
        if (local < 12500u) {
            int sh = (id & 3) * 8;
            uint old = atomicAdd(&cur[local >> 2], 1u << sh);
            int lrank = (old >> sh) & 255;
            int pbase = (pref[id >> 2] >> sh) & 255;
            col[off[id] + pbase + lrank] = oth[i];
        }
    }
}

// ---------------------------------------------------------------------------
// Weight precombine stage 1
__global__ void pre1_kernel(const float* __restrict__ W_ue, const float* __restrict__ W_h_ur,
                            const float* __restrict__ W_re, const float* __restrict__ W_h_ru,
                            const float* __restrict__ b_ue, const float* __restrict__ b_re,
                            float* __restrict__ T1a, float* __restrict__ T1b,
                            float* __restrict__ v1, float* __restrict__ v2) {
    int idx = blockIdx.x * blockDim.x + threadIdx.x;
    if (idx < 32768) {
        int k = idx >> 7, j = idx & 127;
        float acc = 0.f;
        for (int m = 0; m < 128; ++m) acc += W_ue[k * 128 + m] * W_h_ur[m * 128 + j];
        T1a[idx] = acc;
    } else if (idx < 65536) {
        int t = idx - 32768;
        int k = t >> 7, j = t & 127;
        float acc = 0.f;
        for (int m = 0; m < 128; ++m) acc += W_re[k * 128 + m] * W_h_ru[m * 128 + j];
        T1b[t] = acc;
    } else if (idx < 65664) {
        int j = idx - 65536;
        float acc = 0.f;
        for (int m = 0; m < 128; ++m) acc += b_ue[m] * W_h_ur[m * 128 + j];
        v1[j] = acc;
    } else if (idx < 65792) {
        int j = idx - 65664;
        float acc = 0.f;
        for (int m = 0; m < 128; ++m) acc += b_re[m] * W_h_ru[m * 128 + j];
        v2[j] = acc;
    }
}

// Stage 2: Wt = transposed bf16 combined weights + bias vectors
__global__ void pre2_kernel(const float* __restrict__ T1a, const float* __restrict__ T1b,
                            const float* __restrict__ v1, const float* __restrict__ v2,
                            const float* __restrict__ W_o_ur, const float* __restrict__ W_o_ru,
                            const float* __restrict__ b_h_ur, const float* __restrict__ b_h_ru,
                            u16* __restrict__ Wt1, u16* __restrict__ Wt2,
                            float* __restrict__ bbig1, float* __restrict__ bbig2,
                            float* __restrict__ bvC, float* __restrict__ bvD) {
    int idx = blockIdx.x * blockDim.x + threadIdx.x;
    if (idx < 16384) {
        int k = idx >> 6, n = idx & 63;
        float acc = 0.f;
        for (int j = 0; j < 128; ++j) acc += T1a[k * 128 + j] * W_o_ru[j * 64 + n];
        Wt1[n * 256 + k] = (u16)bf_rne(acc);
    } else if (idx < 32768) {
        int t = idx - 16384;
        int k = t >> 6, n = t & 63;
        float acc = 0.f;
        for (int j = 0; j < 128; ++j) acc += T1b[k * 128 + j] * W_o_ur[j * 64 + n];
        Wt2[n * 256 + k] = (u16)bf_rne(acc);
    } else if (idx < 33024) {
        int t = idx - 32768;
        int n = t & 63, which = t >> 6;
        float acc = 0.f;
        if (which == 0)      { for (int j = 0; j < 128; ++j) acc += v1[j] * W_o_ru[j * 64 + n]; bbig1[n] = acc; }
        else if (which == 1) { for (int j = 0; j < 128; ++j) acc += v2[j] * W_o_ur[j * 64 + n]; bbig2[n] = acc; }
        else if (which == 2) { for (int j = 0; j < 128; ++j) acc += b_h_ru[j] * W_o_ur[j * 64 + n]; bvC[n] = acc; }
        else                 { for (int j = 0; j < 128; ++j) acc += b_h_ur[j] * W_o_ru[j * 64 + n]; bvD[n] = acc; }
    }
}

// ---------------------------------------------------------------------------
// MFMA GEMM v6: barrier-free A-staged with NON-TEMPORAL A loads (A is
// single-use per launch; clang ext_vector float4 satisfies the builtin).
__global__ __launch_bounds__(256) void gemm_nt(
    const float* __restrict__ A1, const u16* __restrict__ Wt1,
    const float* __restrict__ bias1, const float* __restrict__ scale1,
    uint* __restrict__ out1,
    const float* __restrict__ A2, const u16* __restrict__ Wt2,
    const float* __restrict__ bias2, const float* __restrict__ scale2,
    uint* __restrict__ out2, int M, int half) {
    const float* A; const u16* Wt; const float* bias; const float* scale; uint* out;
    int blk = blockIdx.x;
    if (blk < half) { A = A1; Wt = Wt1; bias = bias1; scale = scale1; out = out1; }
    else { blk -= half; A = A2; Wt = Wt2; bias = bias2; scale = scale2; out = out2; }
    __shared__ u16 sA[64 * 256];          // 32KB, row stride 512B; wave-private rows
    int tid = threadIdx.x;
    int w = tid >> 6, lane = tid & 63;
    int r0 = blk * 64;
    // ---- stage: wave w loads ITS OWN rows w*16..w*16+15, coalesced, nt ----
    #pragma unroll
    for (int i = 0; i < 16; ++i) {
        int row = w * 16 + i;
        int grow = min(r0 + row, M - 1);
        f32x4 f = __builtin_nontemporal_load(
            (const f32x4*)(A + (size_t)grow * 256 + lane * 4));
        uint2 p;
        p.x = bfpack(f.x, f.y);
        p.y = bfpack(f.z, f.w);
        uint sw = (row & 7) << 4;
        *(uint2*)((char*)sA + row * 512 + ((lane * 8) ^ sw)) = p;
    }
    // NO __syncthreads(): wave reads only rows it wrote itself.
    int l15 = lane & 15, kch = lane >> 4;
    const char* pa = (const char*)sA + (w * 16 + l15) * 512;
    uint swr = (l15 & 7) << 4;
    bf16x8 a[8];
    #pragma unroll
    for (int ks = 0; ks < 8; ++ks)
        a[ks] = *(const bf16x8*)(pa + ((ks * 64 + kch * 16) ^ swr));
    f32x4 acc[4];
    #pragma unroll
    for (int cf = 0; cf < 4; ++cf) acc[cf] = (f32x4){0.f, 0.f, 0.f, 0.f};
    #pragma unroll
    for (int cf = 0; cf < 4; ++cf) {
        const u16* wrow = Wt + (cf * 16 + l15) * 256 + kch * 8;
        #pragma unroll
        for (int ks = 0; ks < 8; ++ks) {
            const bf16x8 b = *(const bf16x8*)(wrow + ks * 32);
            acc[cf] = __builtin_amdgcn_mfma_f32_16x16x32_bf16(a[ks], b, acc[cf], 0, 0, 0);
        }
    }
    float bv[4];
    #pragma unroll
    for (int cf = 0; cf < 4; ++cf) bv[cf] = bias[cf * 16 + l15];
    #pragma unroll
    for (int r = 0; r < 4; ++r) {
        int orow = r0 + w * 16 + kch * 4 + r;
        if (orow < M) {
            float n = scale[orow];
            #pragma unroll
            for (int cf = 0; cf < 4; ++cf) {
                float val = n * acc[cf][r] + n * bv[cf];
                UH hh; hh.h = __floats2half2_rn(val, 0.f);
                ((u16*)out)[(size_t)orow * 64 + cf * 16 + l15] = (u16)(hh.u & 0xffffu);
            }
        }
    }
}

// ---------------------------------------------------------------------------
// CSR gather over fp16 rows: wave = 8 groups x 8 lanes; WAVE-UNIFORM trips;
// nt col reads; PACKED __hadd2 accumulate.
//   MODE 0: v = nm^2*acc + nm*bias          -> fp16 rows
//   MODE 1: v = normalize(nm*acc + bias)    -> fp16 UNIT rows (score-ready)
template <int MODE>
__global__ __launch_bounds__(256) void gather2(
    const uint* __restrict__ fA, const int* __restrict__ offA, const int* __restrict__ colA,
    const float* __restrict__ nmA, const float* __restrict__ bsA, uint* __restrict__ obA,
    const uint* __restrict__ fB, const int* __restrict__ offB, const int* __restrict__ colB,
    const float* __restrict__ nmB, const float* __restrict__ bsB, uint* __restrict__ obB,
    int n) {
    int node = (int)((blockIdx.x * (size_t)blockDim.x + threadIdx.x) >> 6);
    int lane = threadIdx.x & 63;
    if (node >= 2 * n) return;
    const uint* feat; const int* off; const int* col; const float* nmp; const float* bs;
    uint* ob;
    if (node < n) { feat = fA; off = offA; col = colA; nmp = nmA; bs = bsA; ob = obA; }
    else { node -= n; feat = fB; off = offB; col = colB; nmp = nmB; bs = bsB; ob = obB; }
    int g = lane >> 3, j = lane & 7;
    int b = off[node];
    int d = off[node + 1] - b;
    __half2 hz = __floats2half2_rn(0.f, 0.f);
    __half2 hacc[4] = {hz, hz, hz, hz};
    for (int j0 = 0; j0 < d; j0 += 64) {
        int c = (j0 + lane < d) ? __builtin_nontemporal_load(col + b + j0 + lane) : 0;
        int cnt = min(64, d - j0);          // wave-uniform
        int k = 0;
        for (; k + 16 <= cnt; k += 16) {
            int s0 = __shfl(c, k + g);
            int s1 = __shfl(c, k + g + 8);
            U4H u0, u1;
            u0.u = *(const uint4*)(feat + (size_t)s0 * 32 + j * 4);
            u1.u = *(const uint4*)(feat + (size_t)s1 * 32 + j * 4);
            #pragma unroll
            for (int t = 0; t < 4; ++t) hacc[t] = __hadd2(hacc[t], u0.h[t]);
            #pragma unroll
            for (int t = 0; t < 4; ++t) hacc[t] = __hadd2(hacc[t], u1.h[t]);
        }
        if (k + 8 <= cnt) {
            int s0 = __shfl(c, k + g);
            U4H u0; u0.u = *(const uint4*)(feat + (size_t)s0 * 32 + j * 4);
            #pragma unroll
            for (int t = 0; t < 4; ++t) hacc[t] = __hadd2(hacc[t], u0.h[t]);
            k += 8;
        }
        if (k < cnt) {                      // rem in [1,8)
            int rem = cnt - k;
            int sl = k + ((g < rem) ? g : 0);
            int s0 = __shfl(c, sl);         // executed by ALL lanes
            if (g < rem) {
                U4H u0; u0.u = *(const uint4*)(feat + (size_t)s0 * 32 + j * 4);
                #pragma unroll
                for (int t = 0; t < 4; ++t) hacc[t] = __hadd2(hacc[t], u0.h[t]);
            }
        }
    }
    #pragma unroll
    for (int o = 8; o < 64; o <<= 1) {
        #pragma unroll
        for (int t = 0; t < 4; ++t) {
            UH x; x.h = hacc[t];
            x.u = (uint)__shfl_xor((int)x.u, o);
            hacc[t] = __hadd2(hacc[t], x.h);
        }
    }
    float nm = nmp[node];
    float v[8];
    #pragma unroll
    for (int t = 0; t < 4; ++t) {
        float2 f = __half22float2(hacc[t]);
        v[2 * t] = f.x; v[2 * t + 1] = f.y;
    }
    if (MODE == 0) {
        #pragma unroll
        for (int t = 0; t < 8; ++t) v[t] = nm * nm * v[t] + nm * bs[8 * j + t];
    } else {
        float ss = 0.f;
        #pragma unroll
        for (int t = 0; t < 8; ++t) { v[t] = nm * v[t] + bs[8 * j + t]; ss += v[t] * v[t]; }
        #pragma unroll
        for (int o = 1; o < 8; o <<= 1) ss += __shfl_xor(ss, o);   // full row norm
        float inv = 1.0f / fmaxf(sqrtf(ss), 1e-12f);
        #pragma unroll
        for (int t = 0; t < 8; ++t) v[t] *= inv;                   // unit row
    }
    if (g == 0) {
        U4H o4;
        o4.h[0] = __floats2half2_rn(v[0], v[1]);
        o4.h[1] = __floats2half2_rn(v[2], v[3]);
        o4.h[2] = __floats2half2_rn(v[4], v[5]);
        o4.h[3] = __floats2half2_rn(v[6], v[7]);
        *(uint4*)(ob + (size_t)node * 32 + j * 4) = o4.u;
    }
}

// ---------------------------------------------------------------------------
// Cosine scores on pre-normalized fp16 rows: 2 pairs per wave, pos+neg fused.
__global__ __launch_bounds__(256) void score2(
    const uint* __restrict__ U, const uint* __restrict__ R,
    const int* __restrict__ pu, const int* __restrict__ pv,
    const int* __restrict__ nu, const int* __restrict__ nv,
    float* __restrict__ out, int P) {
    int wave = (int)((blockIdx.x * (size_t)blockDim.x + threadIdx.x) >> 6);
    int lane = threadIdx.x & 63;
    int half = lane >> 5, j = lane & 31;
    int pairIdx = wave * 2 + half;
    if (pairIdx >= 2 * P) return;
    int idx = (pairIdx < P) ? pairIdx : pairIdx - P;
    int u = (pairIdx < P) ? pu[idx] : nu[idx];
    int v = (pairIdx < P) ? pv[idx] : nv[idx];
    UH uu, rr;
    uu.u = U[(size_t)u * 32 + j];
    rr.u = R[(size_t)v * 32 + j];
    float2 fu = __half22float2(uu.h);
    float2 fr = __half22float2(rr.h);
    float p = fu.x * fr.x + fu.y * fr.y;
#pragma unroll
    for (int o = 1; o < 32; o <<= 1) p += __shfl_xor(p, o);   // within 32-half
    if (j == 0) out[pairIdx] = p;
}

// ---------------------------------------------------------------------------
extern "C" void kernel_launch(void* const* d_in, const int* in_sizes, int n_in,
                              void* d_out, int out_size, void* d_ws, size_t ws_size,
                              hipStream_t stream) {
    const float* user_feat = (const float*)d_in[0];
    const float* repo_feat = (const float*)d_in[1];
    const int*   e_src     = (const int*)d_in[2];
    const int*   e_dst     = (const int*)d_in[3];
    const int*   pos_u     = (const int*)d_in[4];
    const int*   pos_v     = (const int*)d_in[5];
    const int*   neg_u     = (const int*)d_in[6];
    const int*   neg_v     = (const int*)d_in[7];
    const float* W_ue      = (const float*)d_in[8];
    const float* b_ue      = (const float*)d_in[9];
    const float* W_re      = (const float*)d_in[10];
    const float* b_re      = (const float*)d_in[11];
    const float* W_h_ur    = (const float*)d_in[12];
    const float* b_h_ur    = (const float*)d_in[13];
    const float* W_h_ru    = (const float*)d_in[14];
    const float* b_h_ru    = (const float*)d_in[15];
    const float* W_o_ur    = (const float*)d_in[16];
    const float* b_o_ur    = (const float*)d_in[17];
    const float* W_o_ru    = (const float*)d_in[18];
    const float* b_o_ru    = (const float*)d_in[19];

    const int E  = in_sizes[2];
    const int P  = in_sizes[4];
    const int NN = N_NODES;

    // ---- workspace layout: every region 256B-aligned ----
    char* wp = (char*)d_ws;
    auto alloc = [&](size_t bytes) -> char* {
        char* r = wp;
        wp += (bytes + 255) & ~(size_t)255;
        return r;
    };
    int* degU  = (int*)alloc(2 * (size_t)NN * sizeof(int));
    int* degR  = degU + NN;
    int* offU  = (int*)alloc((NN + 1) * sizeof(int));
    int* offR  = (int*)alloc((NN + 1) * sizeof(int));
    int* colS  = (int*)alloc((size_t)E * sizeof(int));
    int* colD  = (int*)alloc((size_t)E * sizeof(int));
    float* normU = (float*)alloc(2 * (size_t)NN * sizeof(float));
    float* normR = normU + NN;
    int* bsum  = (int*)alloc(2 * SNB * sizeof(int));
    int* bpre  = (int*)alloc(2 * SNB * sizeof(int));
    float* T1a   = (float*)alloc(32768 * sizeof(float));
    float* T1b   = (float*)alloc(32768 * sizeof(float));
    float* v1    = (float*)alloc(128 * sizeof(float));
    float* v2    = (float*)alloc(128 * sizeof(float));
    float* bbig1 = (float*)alloc(64 * sizeof(float));
    float* bbig2 = (float*)alloc(64 * sizeof(float));
    float* bvC   = (float*)alloc(64 * sizeof(float));
    float* bvD   = (float*)alloc(64 * sizeof(float));
    u16* Wt1     = (u16*)alloc(16384 * sizeof(u16));   // [64][256] bf16
    u16* Wt2     = (u16*)alloc(16384 * sizeof(u16));
    uint* bufA   = (uint*)alloc((size_t)NN * 32 * sizeof(uint));   // fp16 rows
    uint* bufB   = (uint*)alloc((size_t)NN * 32 * sizeof(uint));
    uint* bufC   = (uint*)alloc((size_t)NN * 32 * sizeof(uint));
    uint* bufD   = (uint*)alloc((size_t)NN * 32 * sizeof(uint));
    // histogram partials / slice-prefix tables alias bufA/bufB (consumed by
    // fill_det BEFORE gemm writes bufA/bufB).
    uint* partialU = bufA;
    uint* partialR = bufB;

    // ---- 1) per-slice histograms -> degrees + slice prefixes -> scan -> fill ----
    hist_kernel<<<2 * NSL, 256, 0, stream>>>(e_src, e_dst, E, partialU, partialR);
    histreduce<<<(2 * HBINS + 255) / 256, 256, 0, stream>>>(partialU, partialR, degU, degR);
    scanA<<<2 * SNB, 256, 0, stream>>>(degU, degR, bsum, NN);
    scanB<<<1, 64, 0, stream>>>(bsum, bpre);
    scanC<<<2 * SNB, 256, 0, stream>>>(degU, offU, normU, degR, offR, normR, bpre, NN);
    fill_det<<<2 * NSL * 8, 256, 0, stream>>>(e_src, e_dst, E, partialU, partialR,
                                              offU, offR, colS, colD);

    // ---- 2) pre-combined weights ----
    pre1_kernel<<<(65792 + 255) / 256, 256, 0, stream>>>(W_ue, W_h_ur, W_re, W_h_ru,
                                                         b_ue, b_re, T1a, T1b, v1, v2);
    pre2_kernel<<<(33024 + 255) / 256, 256, 0, stream>>>(T1a, T1b, v1, v2, W_o_ur, W_o_ru,
                                                         b_h_ur, b_h_ru, Wt1, Wt2,
                                                         bbig1, bbig2, bvC, bvD);

    // ---- 3) node-level GEMMs (barrier-free A-staged MFMA, nt A-loads) ----
    const int half = (NN + 63) / 64;
    gemm_nt<<<2 * half, 256, 0, stream>>>(user_feat, Wt1, bbig1, normU, bufA,
                                          repo_feat, Wt2, bbig2, normR, bufB, NN, half);

    // ---- 4) layer-1 gathers fused (fp16 out) ----
    const int g2Grid = (int)(((size_t)2 * NN * 64 + 255) / 256);
    gather2<0><<<g2Grid, 256, 0, stream>>>(
        bufA, offR, colD, normR, bvD, bufC,
        bufB, offU, colS, normU, bvC, bufD, NN);

    // ---- 5) layer-2 gathers fused -> normalized fp16 unit rows ----
    gather2<1><<<g2Grid, 256, 0, stream>>>(
        bufC, offU, colS, normU, b_o_ru, bufA,
        bufD, offR, colD, normR, b_o_ur, bufB, NN);

    // ---- 6) cosine scores on unit rows (2 pairs/wave) ----
    float* out = (float*)d_out;
    const int sGrid = (int)(((size_t)P * 64 + 255) / 256);
    score2<<<sGrid, 256, 0, stream>>>(bufA, bufB, pos_u, pos_v, neg_u, neg_v, out, P);
}

// Round 23
// 399.720 us; speedup vs baseline: 1.0696x; 1.0696x over previous
//
#include <hip/hip_runtime.h>
#include <hip/hip_fp16.h>
#include <cstddef>
#include <cstdint>

#define N_NODES 100000
typedef unsigned int uint;
typedef unsigned short u16;
typedef __attribute__((ext_vector_type(8))) short bf16x8;
typedef __attribute__((ext_vector_type(4))) float f32x4;

// ---- bf16 helpers (bit-exact unpack, RNE pack) ------------------------------
__device__ __forceinline__ float bflo(uint u) { return __uint_as_float(u << 16); }
__device__ __forceinline__ float bfhi(uint u) { return __uint_as_float(u & 0xffff0000u); }
__device__ __forceinline__ uint bf_rne(float f) {
    uint u = __float_as_uint(f);
    return (u + 0x7fffu + ((u >> 16) & 1u)) >> 16;
}
__device__ __forceinline__ uint bfpack(float a, float b) {
    return bf_rne(a) | (bf_rne(b) << 16);
}
union U4H { uint4 u; __half2 h[4]; };
union UH  { uint u; __half2 h; };

// ---------------------------------------------------------------------------
// Degree via per-CU LDS histogram, u8-packed (4 ids per u32 word).
#define HBINS 25000   // 100000/4 words, 100KB LDS
#define NSL 128       // slices (must match fill)
__global__ __launch_bounds__(256) void hist_kernel(
    const int* __restrict__ src, const int* __restrict__ dst, int E,
    uint* __restrict__ partialU, uint* __restrict__ partialR) {
    __shared__ uint h[HBINS];
    int b = blockIdx.x;
    const int* ids = (b < NSL) ? src : dst;
    uint* out = ((b < NSL) ? partialU : partialR);
    int slice = (b < NSL) ? b : b - NSL;
    for (int i = threadIdx.x; i < HBINS; i += 256) h[i] = 0;
    __syncthreads();
    int per = (E + NSL - 1) / NSL;
    int lo = slice * per, hi = min(E, lo + per);
    for (int i = lo + threadIdx.x; i < hi; i += 256) {
        int id = ids[i];
        atomicAdd(&h[id >> 2], 1u << ((id & 3) * 8));
    }
    __syncthreads();
    out += (size_t)slice * HBINS;
    for (int i = threadIdx.x; i < HBINS; i += 256) out[i] = h[i];
}

// Reduce per-slice histograms -> degrees + in-place packed-u8 exclusive
// prefix over slices (per node). Safe: degree << 255.
__global__ __launch_bounds__(256) void histreduce(
    uint* __restrict__ partialU, uint* __restrict__ partialR,
    int* __restrict__ degU, int* __restrict__ degR) {
    int idx = blockIdx.x * blockDim.x + threadIdx.x;
    if (idx >= 2 * HBINS) return;
    uint* p = (idx < HBINS) ? partialU : partialR;
    int* deg = (idx < HBINS) ? degU : degR;
    int w = (idx < HBINS) ? idx : idx - HBINS;
    uint r0 = 0, r1 = 0, r2 = 0, r3 = 0;
    for (int b = 0; b < NSL; ++b) {
        size_t k = (size_t)b * HBINS + w;
        uint v = p[k];
        p[k] = r0 | (r1 << 8) | (r2 << 16) | (r3 << 24);   // exclusive prefix
        r0 += v & 255u; r1 += (v >> 8) & 255u; r2 += (v >> 16) & 255u; r3 += v >> 24;
    }
    *(int4*)(deg + 4 * w) = make_int4((int)r0, (int)r1, (int)r2, (int)r3);
}

// ---------------------------------------------------------------------------
// Multi-block exclusive scan of degrees.
#define CHUNK 4096
#define SNB ((N_NODES + CHUNK - 1) / CHUNK)

__global__ __launch_bounds__(256) void scanA(
    const int* __restrict__ degU, const int* __restrict__ degR,
    int* __restrict__ bsum, int n) {
    int b = blockIdx.x;
    int side = b / SNB, blk = b % SNB;
    const int* deg = side ? degR : degU;
    int base = blk * CHUNK;
    int tid = threadIdx.x;
    int s = 0;
    #pragma unroll
    for (int k = 0; k < 16; ++k) {
        int i = base + k * 256 + tid;
        if (i < n) s += deg[i];
    }
    #pragma unroll
    for (int o = 32; o; o >>= 1) s += __shfl_xor(s, o);
    __shared__ int ws[4];
    if ((tid & 63) == 0) ws[tid >> 6] = s;
    __syncthreads();
    if (tid == 0) bsum[b] = ws[0] + ws[1] + ws[2] + ws[3];
}

__global__ void scanB(const int* __restrict__ bsum, int* __restrict__ bpre) {
    if (threadIdx.x == 0) {
        int run = 0;
        for (int i = 0; i < 2 * SNB; ++i) {
            if (i == SNB) run = 0;      // side boundary reset
            bpre[i] = run;
            run += bsum[i];
        }
    }
}

__global__ __launch_bounds__(256) void scanC(
    const int* __restrict__ degU, int* __restrict__ offU, float* __restrict__ normU,
    const int* __restrict__ degR, int* __restrict__ offR, float* __restrict__ normR,
    const int* __restrict__ bpre, int n) {
    int b = blockIdx.x;
    int side = b / SNB, blk = b % SNB;
    const int* deg = side ? degR : degU;
    int* off = side ? offR : offU;
    float* nrm = side ? normR : normU;
    int base = blk * CHUNK;
    int tid = threadIdx.x;
    int p0 = base + tid * 16;
    int e[16];
    #pragma unroll
    for (int k = 0; k < 16; ++k) {
        int i = p0 + k;
        e[k] = (i < n) ? deg[i] : 0;
    }
    int loc = 0;
    #pragma unroll
    for (int k = 0; k < 16; ++k) loc += e[k];
    int lane = tid & 63, wv = tid >> 6;
    int x = loc;
    #pragma unroll
    for (int o = 1; o < 64; o <<= 1) {
        int y = __shfl_up(x, o);
        if (lane >= o) x += y;
    }
    __shared__ int wsum[4];
    if (lane == 63) wsum[wv] = x;
    __syncthreads();
    int wvOff = 0;
    for (int i = 0; i < wv; ++i) wvOff += wsum[i];
    int run = bpre[b] + wvOff + (x - loc);
    if (blk == 0 && tid == 0) off[0] = 0;
    #pragma unroll
    for (int k = 0; k < 16; ++k) {
        int i = p0 + k;
        if (i < n) {
            int v = e[k];
            nrm[i] = (v > 0) ? (1.0f / sqrtf((float)v)) : 0.f;
            run += v;
            off[i + 1] = run;
        }
    }
}

// ---------------------------------------------------------------------------
// Weight precombine stage 1
__global__ void pre1_kernel(const float* __restrict__ W_ue, const float* __restrict__ W_h_ur,
                            const float* __restrict__ W_re, const float* __restrict__ W_h_ru,
                            const float* __restrict__ b_ue, const float* __restrict__ b_re,
                            float* __restrict__ T1a, float* __restrict__ T1b,
                            float* __restrict__ v1, float* __restrict__ v2) {
    int idx = blockIdx.x * blockDim.x + threadIdx.x;
    if (idx < 32768) {
        int k = idx >> 7, j = idx & 127;
        float acc = 0.f;
        for (int m = 0; m < 128; ++m) acc += W_ue[k * 128 + m] * W_h_ur[m * 128 + j];
        T1a[idx] = acc;
    } else if (idx < 65536) {
        int t = idx - 32768;
        int k = t >> 7, j = t & 127;
        float acc = 0.f;
        for (int m = 0; m < 128; ++m) acc += W_re[k * 128 + m] * W_h_ru[m * 128 + j];
        T1b[t] = acc;
    } else if (idx < 65664) {
        int j = idx - 65536;
        float acc = 0.f;
        for (int m = 0; m < 128; ++m) acc += b_ue[m] * W_h_ur[m * 128 + j];
        v1[j] = acc;
    } else if (idx < 65792) {
        int j = idx - 65664;
        float acc = 0.f;
        for (int m = 0; m < 128; ++m) acc += b_re[m] * W_h_ru[m * 128 + j];
        v2[j] = acc;
    }
}

// Stage 2: Wt = transposed bf16 combined weights + bias vectors
__global__ void pre2_kernel(const float* __restrict__ T1a, const float* __restrict__ T1b,
                            const float* __restrict__ v1, const float* __restrict__ v2,
                            const float* __restrict__ W_o_ur, const float* __restrict__ W_o_ru,
                            const float* __restrict__ b_h_ur, const float* __restrict__ b_h_ru,
                            u16* __restrict__ Wt1, u16* __restrict__ Wt2,
                            float* __restrict__ bbig1, float* __restrict__ bbig2,
                            float* __restrict__ bvC, float* __restrict__ bvD) {
    int idx = blockIdx.x * blockDim.x + threadIdx.x;
    if (idx < 16384) {
        int k = idx >> 6, n = idx & 63;
        float acc = 0.f;
        for (int j = 0; j < 128; ++j) acc += T1a[k * 128 + j] * W_o_ru[j * 64 + n];
        Wt1[n * 256 + k] = (u16)bf_rne(acc);
    } else if (idx < 32768) {
        int t = idx - 16384;
        int k = t >> 6, n = t & 63;
        float acc = 0.f;
        for (int j = 0; j < 128; ++j) acc += T1b[k * 128 + j] * W_o_ur[j * 64 + n];
        Wt2[n * 256 + k] = (u16)bf_rne(acc);
    } else if (idx < 33024) {
        int t = idx - 32768;
        int n = t & 63, which = t >> 6;
        float acc = 0.f;
        if (which == 0)      { for (int j = 0; j < 128; ++j) acc += v1[j] * W_o_ru[j * 64 + n]; bbig1[n] = acc; }
        else if (which == 1) { for (int j = 0; j < 128; ++j) acc += v2[j] * W_o_ur[j * 64 + n]; bbig2[n] = acc; }
        else if (which == 2) { for (int j = 0; j < 128; ++j) acc += b_h_ru[j] * W_o_ur[j * 64 + n]; bvC[n] = acc; }
        else                 { for (int j = 0; j < 128; ++j) acc += b_h_ur[j] * W_o_ru[j * 64 + n]; bvD[n] = acc; }
    }
}

// ---------------------------------------------------------------------------
// FUSED fill + gemm: the two are data-independent but complementary (fill is
// BW-saturating @3.4TB/s, gemm is BW-starved @1.2TB/s). One launch lets the
// CU scheduler co-resident them instead of running serially (90+88us).
// Blocks [0, 2048): deterministic CSR fill (zero global atomics).
// Blocks [2048, ..): barrier-free A-staged MFMA gemm with nt A-loads.
#define FILLB (2 * NSL * 8)
__global__ __launch_bounds__(256) void fill_gemm(
    // fill args
    const int* __restrict__ src, const int* __restrict__ dst, int E,
    const uint* __restrict__ prefS, const uint* __restrict__ prefD,
    const int* __restrict__ offS, const int* __restrict__ offD,
    int* __restrict__ colS, int* __restrict__ colD,
    // gemm args
    const float* __restrict__ A1, const u16* __restrict__ Wt1,
    const float* __restrict__ bias1, const float* __restrict__ scale1,
    uint* __restrict__ out1,
    const float* __restrict__ A2, const u16* __restrict__ Wt2,
    const float* __restrict__ bias2, const float* __restrict__ scale2,
    uint* __restrict__ out2, int M, int half) {
    __shared__ char smem[32768];          // fill uses 12.5KB, gemm 32KB
    int tid = threadIdx.x;
    if (blockIdx.x < FILLB) {
        // ================= fill =================
        uint* cur = (uint*)smem;          // [3125]
        int b = blockIdx.x;
        int side = b >> 10;
        int r = b & 1023;
        int x = r & 7;
        int slice = r >> 3;
        const int* ids = side ? dst : src;
        const int* oth = side ? src : dst;
        const uint* pref = (side ? prefD : prefS) + (size_t)slice * HBINS;
        const int* off = side ? offD : offS;
        int* col = side ? colD : colS;
        for (int i = tid; i < 3125; i += 256) cur[i] = 0;
        __syncthreads();
        int per = (E + NSL - 1) / NSL;
        int lo = slice * per, hi = min(E, lo + per);
        int rlo = x * 12500;
        for (int i = lo + tid; i < hi; i += 256) {
            int id = ids[i];
            unsigned local = (unsigned)(id - rlo);
            if (local < 12500u) {
                int sh = (id & 3) * 8;
                uint old = atomicAdd(&cur[local >> 2], 1u << sh);
                int lrank = (old >> sh) & 255;
                int pbase = (pref[id >> 2] >> sh) & 255;
                col[off[id] + pbase + lrank] = oth[i];
            }
        }
    } else {
        // ================= gemm =================
        const float* A; const u16* Wt; const float* bias; const float* scale; uint* out;
        int blk = blockIdx.x - FILLB;
        if (blk < half) { A = A1; Wt = Wt1; bias = bias1; scale = scale1; out = out1; }
        else { blk -= half; A = A2; Wt = Wt2; bias = bias2; scale = scale2; out = out2; }
        u16* sA = (u16*)smem;             // [64*256], row stride 512B
        int w = tid >> 6, lane = tid & 63;
        int r0 = blk * 64;
        #pragma unroll
        for (int i = 0; i < 16; ++i) {
            int row = w * 16 + i;
            int grow = min(r0 + row, M - 1);
            f32x4 f = __builtin_nontemporal_load(
                (const f32x4*)(A + (size_t)grow * 256 + lane * 4));
            uint2 p;
            p.x = bfpack(f.x, f.y);
            p.y = bfpack(f.z, f.w);
            uint sw = (row & 7) << 4;
            *(uint2*)((char*)sA + row * 512 + ((lane * 8) ^ sw)) = p;
        }
        // no barrier: wave reads only rows it wrote itself
        int l15 = lane & 15, kch = lane >> 4;
        const char* pa = (const char*)sA + (w * 16 + l15) * 512;
        uint swr = (l15 & 7) << 4;
        bf16x8 a[8];
        #pragma unroll
        for (int ks = 0; ks < 8; ++ks)
            a[ks] = *(const bf16x8*)(pa + ((ks * 64 + kch * 16) ^ swr));
        f32x4 acc[4];
        #pragma unroll
        for (int cf = 0; cf < 4; ++cf) acc[cf] = (f32x4){0.f, 0.f, 0.f, 0.f};
        #pragma unroll
        for (int cf = 0; cf < 4; ++cf) {
            const u16* wrow = Wt + (cf * 16 + l15) * 256 + kch * 8;
            #pragma unroll
            for (int ks = 0; ks < 8; ++ks) {
                const bf16x8 b = *(const bf16x8*)(wrow + ks * 32);
                acc[cf] = __builtin_amdgcn_mfma_f32_16x16x32_bf16(a[ks], b, acc[cf], 0, 0, 0);
            }
        }
        float bv[4];
        #pragma unroll
        for (int cf = 0; cf < 4; ++cf) bv[cf] = bias[cf * 16 + l15];
        #pragma unroll
        for (int r = 0; r < 4; ++r) {
            int orow = r0 + w * 16 + kch * 4 + r;
            if (orow < M) {
                float n = scale[orow];
                #pragma unroll
                for (int cf = 0; cf < 4; ++cf) {
                    float val = n * acc[cf][r] + n * bv[cf];
                    UH hh; hh.h = __floats2half2_rn(val, 0.f);
                    ((u16*)out)[(size_t)orow * 64 + cf * 16 + l15] = (u16)(hh.u & 0xffffu);
                }
            }
        }
    }
}

// ---------------------------------------------------------------------------
// CSR gather over fp16 rows: wave = 8 groups x 8 lanes; WAVE-UNIFORM trips;
// nt col reads; PACKED __hadd2 accumulate.
//   MODE 0: v = nm^2*acc + nm*bias          -> fp16 rows
//   MODE 1: v = normalize(nm*acc + bias)    -> fp16 UNIT rows (score-ready)
template <int MODE>
__global__ __launch_bounds__(256) void gather2(
    const uint* __restrict__ fA, const int* __restrict__ offA, const int* __restrict__ colA,
    const float* __restrict__ nmA, const float* __restrict__ bsA, uint* __restrict__ obA,
    const uint* __restrict__ fB, const int* __restrict__ offB, const int* __restrict__ colB,
    const float* __restrict__ nmB, const float* __restrict__ bsB, uint* __restrict__ obB,
    int n) {
    int node = (int)((blockIdx.x * (size_t)blockDim.x + threadIdx.x) >> 6);
    int lane = threadIdx.x & 63;
    if (node >= 2 * n) return;
    const uint* feat; const int* off; const int* col; const float* nmp; const float* bs;
    uint* ob;
    if (node < n) { feat = fA; off = offA; col = colA; nmp = nmA; bs = bsA; ob = obA; }
    else { node -= n; feat = fB; off = offB; col = colB; nmp = nmB; bs = bsB; ob = obB; }
    int g = lane >> 3, j = lane & 7;
    int b = off[node];
    int d = off[node + 1] - b;
    __half2 hz = __floats2half2_rn(0.f, 0.f);
    __half2 hacc[4] = {hz, hz, hz, hz};
    for (int j0 = 0; j0 < d; j0 += 64) {
        int c = (j0 + lane < d) ? __builtin_nontemporal_load(col + b + j0 + lane) : 0;
        int cnt = min(64, d - j0);          // wave-uniform
        int k = 0;
        for (; k + 16 <= cnt; k += 16) {
            int s0 = __shfl(c, k + g);
            int s1 = __shfl(c, k + g + 8);
            U4H u0, u1;
            u0.u = *(const uint4*)(feat + (size_t)s0 * 32 + j * 4);
            u1.u = *(const uint4*)(feat + (size_t)s1 * 32 + j * 4);
            #pragma unroll
            for (int t = 0; t < 4; ++t) hacc[t] = __hadd2(hacc[t], u0.h[t]);
            #pragma unroll
            for (int t = 0; t < 4; ++t) hacc[t] = __hadd2(hacc[t], u1.h[t]);
        }
        if (k + 8 <= cnt) {
            int s0 = __shfl(c, k + g);
            U4H u0; u0.u = *(const uint4*)(feat + (size_t)s0 * 32 + j * 4);
            #pragma unroll
            for (int t = 0; t < 4; ++t) hacc[t] = __hadd2(hacc[t], u0.h[t]);
            k += 8;
        }
        if (k < cnt) {                      // rem in [1,8)
            int rem = cnt - k;
            int sl = k + ((g < rem) ? g : 0);
            int s0 = __shfl(c, sl);         // executed by ALL lanes
            if (g < rem) {
                U4H u0; u0.u = *(const uint4*)(feat + (size_t)s0 * 32 + j * 4);
                #pragma unroll
                for (int t = 0; t < 4; ++t) hacc[t] = __hadd2(hacc[t], u0.h[t]);
            }
        }
    }
    #pragma unroll
    for (int o = 8; o < 64; o <<= 1) {
        #pragma unroll
        for (int t = 0; t < 4; ++t) {
            UH x; x.h = hacc[t];
            x.u = (uint)__shfl_xor((int)x.u, o);
            hacc[t] = __hadd2(hacc[t], x.h);
        }
    }
    float nm = nmp[node];
    float v[8];
    #pragma unroll
    for (int t = 0; t < 4; ++t) {
        float2 f = __half22float2(hacc[t]);
        v[2 * t] = f.x; v[2 * t + 1] = f.y;
    }
    if (MODE == 0) {
        #pragma unroll
        for (int t = 0; t < 8; ++t) v[t] = nm * nm * v[t] + nm * bs[8 * j + t];
    } else {
        float ss = 0.f;
        #pragma unroll
        for (int t = 0; t < 8; ++t) { v[t] = nm * v[t] + bs[8 * j + t]; ss += v[t] * v[t]; }
        #pragma unroll
        for (int o = 1; o < 8; o <<= 1) ss += __shfl_xor(ss, o);   // full row norm
        float inv = 1.0f / fmaxf(sqrtf(ss), 1e-12f);
        #pragma unroll
        for (int t = 0; t < 8; ++t) v[t] *= inv;                   // unit row
    }
    if (g == 0) {
        U4H o4;
        o4.h[0] = __floats2half2_rn(v[0], v[1]);
        o4.h[1] = __floats2half2_rn(v[2], v[3]);
        o4.h[2] = __floats2half2_rn(v[4], v[5]);
        o4.h[3] = __floats2half2_rn(v[6], v[7]);
        *(uint4*)(ob + (size_t)node * 32 + j * 4) = o4.u;
    }
}

// ---------------------------------------------------------------------------
// Cosine scores on pre-normalized fp16 rows: 2 pairs per wave, pos+neg fused.
__global__ __launch_bounds__(256) void score2(
    const uint* __restrict__ U, const uint* __restrict__ R,
    const int* __restrict__ pu, const int* __restrict__ pv,
    const int* __restrict__ nu, const int* __restrict__ nv,
    float* __restrict__ out, int P) {
    int wave = (int)((blockIdx.x * (size_t)blockDim.x + threadIdx.x) >> 6);
    int lane = threadIdx.x & 63;
    int half = lane >> 5, j = lane & 31;
    int pairIdx = wave * 2 + half;
    if (pairIdx >= 2 * P) return;
    int idx = (pairIdx < P) ? pairIdx : pairIdx - P;
    int u = (pairIdx < P) ? pu[idx] : nu[idx];
    int v = (pairIdx < P) ? pv[idx] : nv[idx];
    UH uu, rr;
    uu.u = U[(size_t)u * 32 + j];
    rr.u = R[(size_t)v * 32 + j];
    float2 fu = __half22float2(uu.h);
    float2 fr = __half22float2(rr.h);
    float p = fu.x * fr.x + fu.y * fr.y;
#pragma unroll
    for (int o = 1; o < 32; o <<= 1) p += __shfl_xor(p, o);   // within 32-half
    if (j == 0) out[pairIdx] = p;
}

// ---------------------------------------------------------------------------
extern "C" void kernel_launch(void* const* d_in, const int* in_sizes, int n_in,
                              void* d_out, int out_size, void* d_ws, size_t ws_size,
                              hipStream_t stream) {
    const float* user_feat = (const float*)d_in[0];
    const float* repo_feat = (const float*)d_in[1];
    const int*   e_src     = (const int*)d_in[2];
    const int*   e_dst     = (const int*)d_in[3];
    const int*   pos_u     = (const int*)d_in[4];
    const int*   pos_v     = (const int*)d_in[5];
    const int*   neg_u     = (const int*)d_in[6];
    const int*   neg_v     = (const int*)d_in[7];
    const float* W_ue      = (const float*)d_in[8];
    const float* b_ue      = (const float*)d_in[9];
    const float* W_re      = (const float*)d_in[10];
    const float* b_re      = (const float*)d_in[11];
    const float* W_h_ur    = (const float*)d_in[12];
    const float* b_h_ur    = (const float*)d_in[13];
    const float* W_h_ru    = (const float*)d_in[14];
    const float* b_h_ru    = (const float*)d_in[15];
    const float* W_o_ur    = (const float*)d_in[16];
    const float* b_o_ur    = (const float*)d_in[17];
    const float* W_o_ru    = (const float*)d_in[18];
    const float* b_o_ru    = (const float*)d_in[19];

    const int E  = in_sizes[2];
    const int P  = in_sizes[4];
    const int NN = N_NODES;

    // ---- workspace layout: every region 256B-aligned ----
    char* wp = (char*)d_ws;
    auto alloc = [&](size_t bytes) -> char* {
        char* r = wp;
        wp += (bytes + 255) & ~(size_t)255;
        return r;
    };
    int* degU  = (int*)alloc(2 * (size_t)NN * sizeof(int));
    int* degR  = degU + NN;
    int* offU  = (int*)alloc((NN + 1) * sizeof(int));
    int* offR  = (int*)alloc((NN + 1) * sizeof(int));
    int* colS  = (int*)alloc((size_t)E * sizeof(int));
    int* colD  = (int*)alloc((size_t)E * sizeof(int));
    float* normU = (float*)alloc(2 * (size_t)NN * sizeof(float));
    float* normR = normU + NN;
    int* bsum  = (int*)alloc(2 * SNB * sizeof(int));
    int* bpre  = (int*)alloc(2 * SNB * sizeof(int));
    float* T1a   = (float*)alloc(32768 * sizeof(float));
    float* T1b   = (float*)alloc(32768 * sizeof(float));
    float* v1    = (float*)alloc(128 * sizeof(float));
    float* v2    = (float*)alloc(128 * sizeof(float));
    float* bbig1 = (float*)alloc(64 * sizeof(float));
    float* bbig2 = (float*)alloc(64 * sizeof(float));
    float* bvC   = (float*)alloc(64 * sizeof(float));
    float* bvD   = (float*)alloc(64 * sizeof(float));
    u16* Wt1     = (u16*)alloc(16384 * sizeof(u16));   // [64][256] bf16
    u16* Wt2     = (u16*)alloc(16384 * sizeof(u16));
    uint* bufA   = (uint*)alloc((size_t)NN * 32 * sizeof(uint));   // fp16 rows
    uint* bufB   = (uint*)alloc((size_t)NN * 32 * sizeof(uint));
    uint* bufC   = (uint*)alloc((size_t)NN * 32 * sizeof(uint));
    uint* bufD   = (uint*)alloc((size_t)NN * 32 * sizeof(uint));
    // partials get their OWN storage now (fused fill+gemm: gemm writes
    // bufA/bufB while fill reads the prefix tables).
    uint* partialU = (uint*)alloc((size_t)NSL * HBINS * sizeof(uint));
    uint* partialR = (uint*)alloc((size_t)NSL * HBINS * sizeof(uint));

    // ---- 1) per-slice histograms -> degrees + slice prefixes -> scan ----
    hist_kernel<<<2 * NSL, 256, 0, stream>>>(e_src, e_dst, E, partialU, partialR);
    histreduce<<<(2 * HBINS + 255) / 256, 256, 0, stream>>>(partialU, partialR, degU, degR);
    scanA<<<2 * SNB, 256, 0, stream>>>(degU, degR, bsum, NN);
    scanB<<<1, 64, 0, stream>>>(bsum, bpre);
    scanC<<<2 * SNB, 256, 0, stream>>>(degU, offU, normU, degR, offR, normR, bpre, NN);

    // ---- 2) pre-combined weights ----
    pre1_kernel<<<(65792 + 255) / 256, 256, 0, stream>>>(W_ue, W_h_ur, W_re, W_h_ru,
                                                         b_ue, b_re, T1a, T1b, v1, v2);
    pre2_kernel<<<(33024 + 255) / 256, 256, 0, stream>>>(T1a, T1b, v1, v2, W_o_ur, W_o_ru,
                                                         b_h_ur, b_h_ru, Wt1, Wt2,
                                                         bbig1, bbig2, bvC, bvD);

    // ---- 3) FUSED fill + gemm (independent, complementary BW profiles) ----
    const int half = (NN + 63) / 64;
    fill_gemm<<<FILLB + 2 * half, 256, 0, stream>>>(
        e_src, e_dst, E, partialU, partialR, offU, offR, colS, colD,
        user_feat, Wt1, bbig1, normU, bufA,
        repo_feat, Wt2, bbig2, normR, bufB, NN, half);

    // ---- 4) layer-1 gathers fused (fp16 out) ----
    const int g2Grid = (int)(((size_t)2 * NN * 64 + 255) / 256);
    gather2<0><<<g2Grid, 256, 0, stream>>>(
        bufA, offR, colD, normR, bvD, bufC,
        bufB, offU, colS, normU, bvC, bufD, NN);

    // ---- 5) layer-2 gathers fused -> normalized fp16 unit rows ----
    gather2<1><<<g2Grid, 256, 0, stream>>>(
        bufC, offU, colS, normU, b_o_ru, bufA,
        bufD, offR, colD, normR, b_o_ur, bufB, NN);

    // ---- 6) cosine scores on unit rows (2 pairs/wave) ----
    float* out = (float*)d_out;
    const int sGrid = (int)(((size_t)P * 64 + 255) / 256);
    score2<<<sGrid, 256, 0, stream>>>(bufA, bufB, pos_u, pos_v, neg_u, neg_v, out, P);
}